// Round 10
// baseline (153.673 us; speedup 1.0000x reference)
//
#include <hip/hip_runtime.h>
#include <cstdint>
#include <cstddef>

#define AS1 __attribute__((address_space(1)))
#define AS3 __attribute__((address_space(3)))

typedef __bf16 bf16x8 __attribute__((ext_vector_type(8)));
typedef __bf16 bf16x4 __attribute__((ext_vector_type(4)));
typedef float  f32x4  __attribute__((ext_vector_type(4)));
typedef float  f32x16 __attribute__((ext_vector_type(16)));
typedef unsigned int u32x4 __attribute__((ext_vector_type(4)));

#define MFMA_BF16(a, b, c) __builtin_amdgcn_mfma_f32_16x16x32_bf16((a), (b), (c), 0, 0, 0)
#define MFMA32(a, b, c)    __builtin_amdgcn_mfma_f32_32x32x16_bf16((a), (b), (c), 0, 0, 0)

// async global->LDS, 16B/lane. LDS base wave-uniform; HW adds lane*16. Global addr per-lane.
__device__ __forceinline__ void gload16(const __bf16* g, __bf16* l) {
  __builtin_amdgcn_global_load_lds((AS1 void*)(uintptr_t)g, (AS3 void*)l, 16, 0, 0);
}

__device__ __forceinline__ unsigned int cvtpk_bf16(float lo, float hi) {
  unsigned int r;
  asm("v_cvt_pk_bf16_f32 %0, %1, %2" : "=v"(r) : "v"(lo), "v"(hi));
  return r;
}

// v_permlane32_swap_b32 a, b : a[32:63] <-> b[0:31]
__device__ __forceinline__ void permswap(unsigned int& a, unsigned int& b) {
  asm volatile("v_permlane32_swap_b32 %0, %1" : "+v"(a), "+v"(b));
}

// raw v_exp_f32: computes 2^x
__device__ __forceinline__ float exp2_fast(float x) {
  float r;
  asm("v_exp_f32 %0, %1" : "=v"(r) : "v"(x));
  return r;
}

#define LOG2E 1.4426950408889634f

// ---------------- fp32 -> bf16 conversion (5 tensors) + mask-zero scan, one launch ----------------
__global__ void cvt_all_kernel(
    const float* __restrict__ hs, const float* __restrict__ qw, const float* __restrict__ kw,
    const float* __restrict__ vw, const float* __restrict__ ow,
    __bf16* __restrict__ Xb, __bf16* __restrict__ qwb, __bf16* __restrict__ kwb,
    __bf16* __restrict__ vwb, __bf16* __restrict__ owb,
    const unsigned long long* __restrict__ mask, int* __restrict__ flag)
{
  const int gid = blockIdx.x * blockDim.x + threadIdx.x;
  const int stride = gridDim.x * blockDim.x;
  for (int i = gid; i < 1179648; i += stride) {
    const float* s; __bf16* d; int o;
    if (i < 524288)       { s = hs; d = Xb;  o = i; }
    else if (i < 786432)  { s = qw; d = qwb; o = i - 524288; }
    else if (i < 917504)  { s = kw; d = kwb; o = i - 786432; }
    else if (i < 1048576) { s = vw; d = vwb; o = i - 917504; }
    else                  { s = ow; d = owb; o = i - 1048576; }
    const float4* p = (const float4*)(s + (size_t)o * 8);
    float4 a = p[0], b = p[1];
    bf16x8 v;
    v[0] = (__bf16)a.x; v[1] = (__bf16)a.y; v[2] = (__bf16)a.z; v[3] = (__bf16)a.w;
    v[4] = (__bf16)b.x; v[5] = (__bf16)b.y; v[6] = (__bf16)b.z; v[7] = (__bf16)b.w;
    *(bf16x8*)(d + (size_t)o * 8) = v;
  }
  bool nz = false;
  for (int i = gid; i < 2097152; i += stride) nz |= (mask[i] != 0ull);
  if (nz) atomicOr(flag, 1);
}

// ---------------- fused QGKV projection (bf16 in, bf16 out, fp32 acc), 2-phase dbuf ----------------
__global__ __launch_bounds__(256) void proj_kernel(
    const __bf16* __restrict__ X,
    const __bf16* __restrict__ qw, const float* __restrict__ qb,
    const __bf16* __restrict__ kw, const float* __restrict__ kb,
    const __bf16* __restrict__ vw, const float* __restrict__ vb,
    __bf16* __restrict__ Qo, __bf16* __restrict__ Ko,
    __bf16* __restrict__ VTo, __bf16* __restrict__ Go)
{
  __shared__ __bf16 As[2][128][64];
  __shared__ __bf16 Bs[2][128][64];

  const int bid = blockIdx.x;
  const int r = bid >> 3;
  // ntile fastest within XCD: 4 W-panels (1MB) stay L2-hot, X panel reused by 4 consecutive blocks
  const int ntile = (bid & 7) * 4 + (r & 3);
  const int mtile = r >> 2;
  const int m0 = mtile * 128;
  const int n0 = ntile * 128;

  const __bf16* W; const float* bias; int nb;
  if (n0 < 2048)      { W = qw; bias = qb; nb = n0; }
  else if (n0 < 3072) { W = kw; bias = kb; nb = n0 - 2048; }
  else                { W = vw; bias = vb; nb = n0 - 3072; }

  const int tid = threadIdx.x;
  const int wv = tid >> 6, ln = tid & 63;
  const int wr = wv >> 1, wc = wv & 1;
  const int qr = ln & 15, qg = ln >> 4;
  const int lrow = ln >> 3, lcol = (ln & 7) * 8;

  f32x4 acc[4][4];
#pragma unroll
  for (int m = 0; m < 4; ++m)
#pragma unroll
    for (int n = 0; n < 4; ++n) acc[m][n] = 0.f;

  __bf16 (*Asc)[64] = As[0], (*Asn)[64] = As[1];
  __bf16 (*Bsc)[64] = Bs[0], (*Bsn)[64] = Bs[1];

  // prologue: stage k-tile 0 into current
#pragma unroll
  for (int i = 0; i < 4; ++i) {
    const int rb = i * 32 + wv * 8;
    gload16(X + (size_t)(m0 + rb + lrow) * 1024 + lcol, &Asc[rb][0]);
    gload16(W + (size_t)(nb + rb + lrow) * 1024 + lcol, &Bsc[rb][0]);
  }
  __syncthreads();

  for (int t = 0; t < 16; ++t) {
    if (t < 15) {
      const int k0 = (t + 1) * 64;
#pragma unroll
      for (int i = 0; i < 4; ++i) {
        const int rb = i * 32 + wv * 8;
        gload16(X + (size_t)(m0 + rb + lrow) * 1024 + k0 + lcol, &Asn[rb][0]);
        gload16(W + (size_t)(nb + rb + lrow) * 1024 + k0 + lcol, &Bsn[rb][0]);
      }
    }
#pragma unroll
    for (int kk = 0; kk < 2; ++kk) {
      bf16x8 af[4], bfv[4];
#pragma unroll
      for (int m = 0; m < 4; ++m) af[m] = *(const bf16x8*)&Asc[wr * 64 + m * 16 + qr][kk * 32 + qg * 8];
#pragma unroll
      for (int n = 0; n < 4; ++n) bfv[n] = *(const bf16x8*)&Bsc[wc * 64 + n * 16 + qr][kk * 32 + qg * 8];
#pragma unroll
      for (int m = 0; m < 4; ++m)
#pragma unroll
        for (int n = 0; n < 4; ++n) acc[m][n] = MFMA_BF16(af[m], bfv[n], acc[m][n]);
    }
    __syncthreads();   // drains vmcnt (next tile staged) + orders LDS reuse
    __bf16 (*ta)[64] = Asc; Asc = Asn; Asn = ta;
    __bf16 (*tb)[64] = Bsc; Bsc = Bsn; Bsn = tb;
  }

  // epilogue: C/D layout col=lane&15, row=(lane>>4)*4+reg
#pragma unroll
  for (int m = 0; m < 4; ++m) {
    const int gm0 = m0 + wr * 64 + m * 16 + qg * 4;
    const int b = gm0 >> 11;
    const int s = gm0 & 2047;
#pragma unroll
    for (int n = 0; n < 4; ++n) {
      const int nl = wc * 64 + n * 16 + qr;
      const float bb = bias[nb + nl];
      if (n0 < 1024) {            // Q -> [b,h,s,d], pre-scaled by log2e/sqrt(d) (exp2-domain softmax)
        const int col = n0 + nl, hh = col >> 6, dd = col & 63;
        __bf16* dst = Qo + ((size_t)((b << 4) + hh)) * 131072 + (size_t)s * 64 + dd;
#pragma unroll
        for (int rr = 0; rr < 4; ++rr) dst[(size_t)rr * 64] = (__bf16)((acc[m][n][rr] + bb) * (0.125f * LOG2E));
      } else if (n0 < 2048) {     // gate -> sigmoid -> [token, h*64+d]
        const int j = n0 - 1024 + nl;
        __bf16* dst = Go + (size_t)gm0 * 1024 + j;
#pragma unroll
        for (int rr = 0; rr < 4; ++rr) {
          const float v = acc[m][n][rr] + bb;
          dst[(size_t)rr * 1024] = (__bf16)(1.f / (1.f + __expf(-v)));
        }
      } else if (n0 < 3072) {     // K -> [b,h,s,d]
        const int j = n0 - 2048 + nl, hh = j >> 6, dd = j & 63;
        __bf16* dst = Ko + ((size_t)((b << 4) + hh)) * 131072 + (size_t)s * 64 + dd;
#pragma unroll
        for (int rr = 0; rr < 4; ++rr) dst[(size_t)rr * 64] = (__bf16)(acc[m][n][rr] + bb);
      } else {                    // V -> transposed [b,h,d,s]
        const int j = n0 - 3072 + nl, hh = j >> 6, dd = j & 63;
        bf16x4 pv;
#pragma unroll
        for (int rr = 0; rr < 4; ++rr) pv[rr] = (__bf16)(acc[m][n][rr] + bb);
        *(bf16x4*)(VTo + ((size_t)((b << 4) + hh)) * 131072 + (size_t)dd * 2048 + s) = pv;
      }
    }
  }
}

// ---------------- flash attention: split-KV x2, LDS-staged, swapped-QK^T, exp2 softmax ----------------
// Block = 4 waves (256 thr) = (head, 64 q rows). Wave w: qsub = w&1 (32 q), halfsel = w>>1
// (kv in [halfsel*1024, +1024)). Single-buffered per-half K/V tiles (64kv x 64d) with the
// 16B-granule XOR swizzle; grid 1024 -> 4096 waves = 16/CU, 4 blocks/CU (LDS 33KB).
// End: partials to reused LDS, log2-domain combine, gate, store.
__global__ __launch_bounds__(256, 4) void attn_kernel(
    const __bf16* __restrict__ Qb, const __bf16* __restrict__ Kb,
    const __bf16* __restrict__ VT, const __bf16* __restrict__ G,
    const float* __restrict__ mask, const int* __restrict__ flag,
    __bf16* __restrict__ attn)
{
  __shared__ __bf16 KVsh[2][2][32][128];  // [K/V][halfsel][row][256B], 32 KB
  __shared__ float ML0[2][64], ML1[2][64];  // running max / sum per [halfsel][q]

  const int bid = blockIdx.x;    // 1024 = 8 xcd * (4 heads * 32 qblocks)
  const int y = bid >> 3;        // 0..127
  const int hl = (bid & 7) * 4 + (y >> 5);  // 4 heads per XCD
  const int q0 = (y & 31) * 64;
  const int tid = threadIdx.x;
  const int w = tid >> 6;
  const int qsub = w & 1;
  const int halfsel = w >> 1;
  const int ln = tid & 63;
  const int lq = ln & 31;
  const int hi = ln >> 5;
  const int qg0 = q0 + qsub * 32;           // this lane's 32-q tile base
  const int b = hl >> 4, h = hl & 15;

  const __bf16* Qh = Qb + (size_t)hl * 131072;
  const __bf16* Kh = Kb + (size_t)hl * 131072 + halfsel * 1024 * 64;  // kv-row offset
  const __bf16* Vh = VT + (size_t)hl * 131072 + halfsel * 1024;       // kv-col offset

  // staging source offsets: wave-in-pair wi covers physical rows wi*16 + i*4 + (ln>>4), i=0..3
  const int wi = qsub;
  int kco[4], vco[4], ldst[4];
#pragma unroll
  for (int i = 0; i < 4; ++i) {
    const int prow = wi * 16 + i * 4 + (ln >> 4);
    const int bphys = (ln & 15) * 16;
    const int blog = bphys ^ ((prow & 15) << 4);
    const int sub = blog >> 7;              // K: kv-half-of-64 | V: d-half
    const int col = (blog & 127) >> 1;      // K: d | V: kv-local
    kco[i] = (sub * 32 + prow) * 64 + col;
    vco[i] = (sub * 32 + prow) * 2048 + col;
    ldst[i] = (wi * 16 + i * 4) * 256;
  }
  const int swz = (lq & 15) << 4;
  const int krow = lq * 256;

  char* Kc = (char*)&KVsh[0][halfsel][0][0];
  char* Vc = (char*)&KVsh[1][halfsel][0][0];

  // Q (pre-scaled to log2 domain): frag ks: Q[qg0+lq][16ks+8hi+0..7]
  bf16x8 qf[4];
#pragma unroll
  for (int ks = 0; ks < 4; ++ks)
    qf[ks] = *(const bf16x8*)(Qh + (size_t)(qg0 + lq) * 64 + ks * 16 + hi * 8);

  f32x16 o0, o1;
#pragma unroll
  for (int i = 0; i < 16; ++i) { o0[i] = 0.f; o1[i] = 0.f; }
  float mrun = -1e30f, lrun = 0.f;

  const bool um = (*flag) != 0;

  for (int c = 0; c < 16; ++c) {
    const int kv0 = c * 64;  // local to this half
    // stage this half's chunk (K 8KB + V 8KB by the 2 waves of the pair)
#pragma unroll
    for (int i = 0; i < 4; ++i) {
      gload16(Kh + kv0 * 64 + kco[i], (__bf16*)(Kc + ldst[i]));
      gload16(Vh + kv0 + vco[i],      (__bf16*)(Vc + ldst[i]));
    }
    __syncthreads();   // vmcnt drain + visibility

#pragma unroll
    for (int s32 = 0; s32 < 2; ++s32) {
      bf16x8 kf[4];
#pragma unroll
      for (int ks = 0; ks < 4; ++ks)
        kf[ks] = *(const bf16x8*)(Kc + krow + ((s32 * 128 + ks * 32 + hi * 16) ^ swz));

      f32x16 s;
#pragma unroll
      for (int i = 0; i < 16; ++i) s[i] = 0.f;
      __builtin_amdgcn_s_setprio(1);
#pragma unroll
      for (int ks = 0; ks < 4; ++ks) s = MFMA32(kf[ks], qf[ks], s);
      __builtin_amdgcn_s_setprio(0);

      float p[16];
      if (um) {
        const size_t mrow = (size_t)(qg0 + lq) * 2048 + halfsel * 1024 + kv0 + s32 * 32;
#pragma unroll
        for (int i = 0; i < 16; ++i)
          p[i] = s[i] + mask[mrow + (i & 3) + 8 * (i >> 2) + 4 * hi] * LOG2E;
      } else {
#pragma unroll
        for (int i = 0; i < 16; ++i) p[i] = s[i];
      }

      // row max over 32 kv
      float t = fmaxf(fmaxf(p[0], p[1]), p[2]);
      t = fmaxf(fmaxf(t, p[3]), p[4]);
      t = fmaxf(fmaxf(t, p[5]), p[6]);
      t = fmaxf(fmaxf(t, p[7]), p[8]);
      t = fmaxf(fmaxf(t, p[9]), p[10]);
      t = fmaxf(fmaxf(t, p[11]), p[12]);
      t = fmaxf(fmaxf(t, p[13]), p[14]);
      t = fmaxf(t, p[15]);
      t = fmaxf(t, __shfl_xor(t, 32));

      // defer-max: rescale only when running max grows by > 8
      if (t > mrun + 8.f) {
        const float al = exp2_fast(mrun - t);
        mrun = t;
        lrun *= al;
#pragma unroll
        for (int i = 0; i < 16; ++i) { o0[i] *= al; o1[i] *= al; }
      }

      float ps = 0.f;
#pragma unroll
      for (int i = 0; i < 16; ++i) { p[i] = exp2_fast(p[i] - mrun); ps += p[i]; }
      lrun += ps;

      // pack P into B-frag layout
      bf16x8 pa[2];
#pragma unroll
      for (int ks = 0; ks < 2; ++ks) {
        unsigned int c0 = cvtpk_bf16(p[8 * ks + 0], p[8 * ks + 1]);
        unsigned int c1 = cvtpk_bf16(p[8 * ks + 2], p[8 * ks + 3]);
        unsigned int c2 = cvtpk_bf16(p[8 * ks + 4], p[8 * ks + 5]);
        unsigned int c3 = cvtpk_bf16(p[8 * ks + 6], p[8 * ks + 7]);
        permswap(c0, c2);
        permswap(c1, c3);
        u32x4 wvv; wvv.x = c0; wvv.y = c1; wvv.z = c2; wvv.w = c3;
        pa[ks] = __builtin_bit_cast(bf16x8, wvv);
      }

      // PV from swizzled V tile
      __builtin_amdgcn_s_setprio(1);
#pragma unroll
      for (int ks = 0; ks < 2; ++ks) {
        const int kvb = s32 * 64 + ks * 32 + hi * 16;
        bf16x8 v0 = *(const bf16x8*)(Vc + krow + ((0 + kvb) ^ swz));
        bf16x8 v1 = *(const bf16x8*)(Vc + krow + ((128 + kvb) ^ swz));
        o0 = MFMA32(v0, pa[ks], o0);
        o1 = MFMA32(v1, pa[ks], o1);
      }
      __builtin_amdgcn_s_setprio(0);
    }
    __syncthreads();   // pair done reading before next stage overwrites
  }

  // dump partials: Obuf[halfsel][d][q] over reused K/V LDS (conflict-free both sides)
  lrun += __shfl_xor(lrun, 32);
  float* Obuf = (float*)&KVsh[0][0][0][0];
#pragma unroll
  for (int r = 0; r < 16; ++r) {
    const int d0 = (r & 3) + 8 * (r >> 2) + 4 * hi;
    Obuf[halfsel * 4096 + d0 * 64 + qsub * 32 + lq] = o0[r];
    Obuf[halfsel * 4096 + (d0 + 32) * 64 + qsub * 32 + lq] = o1[r];
  }
  if (hi == 0) { ML0[halfsel][qsub * 32 + lq] = mrun; ML1[halfsel][qsub * 32 + lq] = lrun; }
  __syncthreads();

  // combine: thread t -> q = t&63, d in [seg*16, seg*16+16)
  {
    const int cq = tid & 63;
    const int seg = tid >> 6;
    const float m0 = ML0[0][cq], m1 = ML0[1][cq];
    const float M = fmaxf(m0, m1);
    const float e0 = exp2_fast(m0 - M), e1 = exp2_fast(m1 - M);
    const float L = e0 * ML1[0][cq] + e1 * ML1[1][cq];
    const float inv = 1.f / L;
    const size_t base = ((size_t)(b * 2048 + q0 + cq)) * 1024 + h * 64 + seg * 16;
    bf16x8 g0 = *(const bf16x8*)(G + base);
    bf16x8 g1 = *(const bf16x8*)(G + base + 8);
    bf16x8 r0, r1;
#pragma unroll
    for (int j = 0; j < 8; ++j) {
      const int d = seg * 16 + j;
      const float sacc = e0 * Obuf[d * 64 + cq] + e1 * Obuf[4096 + d * 64 + cq];
      r0[j] = (__bf16)(sacc * inv * (float)g0[j]);
    }
#pragma unroll
    for (int j = 0; j < 8; ++j) {
      const int d = seg * 16 + 8 + j;
      const float sacc = e0 * Obuf[d * 64 + cq] + e1 * Obuf[4096 + d * 64 + cq];
      r1[j] = (__bf16)(sacc * inv * (float)g1[j]);
    }
    *(bf16x8*)(attn + base) = r0;
    *(bf16x8*)(attn + base + 8) = r1;
  }
}

// ---------------- O projection (bf16 in, fp32 out), 2-phase dbuf ----------------
__global__ __launch_bounds__(256) void oproj_kernel(
    const __bf16* __restrict__ A, const __bf16* __restrict__ ow,
    const float* __restrict__ ob, float* __restrict__ C)
{
  __shared__ __bf16 As[2][128][64];
  __shared__ __bf16 Bs[2][128][64];
  const int bid = blockIdx.x;
  const int ntile = bid & 7;
  const int mtile = bid >> 3;
  const int m0 = mtile * 128, n0 = ntile * 128;

  const int tid = threadIdx.x;
  const int wv = tid >> 6, ln = tid & 63;
  const int wr = wv >> 1, wc = wv & 1;
  const int qr = ln & 15, qg = ln >> 4;
  const int lrow = ln >> 3, lcol = (ln & 7) * 8;

  f32x4 acc[4][4];
#pragma unroll
  for (int m = 0; m < 4; ++m)
#pragma unroll
    for (int n = 0; n < 4; ++n) acc[m][n] = 0.f;

  __bf16 (*Asc)[64] = As[0], (*Asn)[64] = As[1];
  __bf16 (*Bsc)[64] = Bs[0], (*Bsn)[64] = Bs[1];

#pragma unroll
  for (int i = 0; i < 4; ++i) {
    const int rb = i * 32 + wv * 8;
    gload16(A  + (size_t)(m0 + rb + lrow) * 1024 + lcol, &Asc[rb][0]);
    gload16(ow + (size_t)(n0 + rb + lrow) * 1024 + lcol, &Bsc[rb][0]);
  }
  __syncthreads();

  for (int t = 0; t < 16; ++t) {
    if (t < 15) {
      const int k0 = (t + 1) * 64;
#pragma unroll
      for (int i = 0; i < 4; ++i) {
        const int rb = i * 32 + wv * 8;
        gload16(A  + (size_t)(m0 + rb + lrow) * 1024 + k0 + lcol, &Asn[rb][0]);
        gload16(ow + (size_t)(n0 + rb + lrow) * 1024 + k0 + lcol, &Bsn[rb][0]);
      }
    }
#pragma unroll
    for (int kk = 0; kk < 2; ++kk) {
      bf16x8 af[4], bfv[4];
#pragma unroll
      for (int m = 0; m < 4; ++m) af[m] = *(const bf16x8*)&Asc[wr * 64 + m * 16 + qr][kk * 32 + qg * 8];
#pragma unroll
      for (int n = 0; n < 4; ++n) bfv[n] = *(const bf16x8*)&Bsc[wc * 64 + n * 16 + qr][kk * 32 + qg * 8];
#pragma unroll
      for (int m = 0; m < 4; ++m)
#pragma unroll
        for (int n = 0; n < 4; ++n) acc[m][n] = MFMA_BF16(af[m], bfv[n], acc[m][n]);
    }
    __syncthreads();
    __bf16 (*ta)[64] = Asc; Asc = Asn; Asn = ta;
    __bf16 (*tb)[64] = Bsc; Bsc = Bsn; Bsn = tb;
  }

#pragma unroll
  for (int m = 0; m < 4; ++m) {
    const int gm0 = m0 + wr * 64 + m * 16 + qg * 4;
#pragma unroll
    for (int n = 0; n < 4; ++n) {
      const int gn = n0 + wc * 64 + n * 16 + qr;
      const float bb = ob[gn];
      float* dst = C + (size_t)gm0 * 1024 + gn;
#pragma unroll
      for (int rr = 0; rr < 4; ++rr) dst[(size_t)rr * 1024] = acc[m][n][rr] + bb;
    }
  }
}

extern "C" void kernel_launch(void* const* d_in, const int* in_sizes, int n_in,
                              void* d_out, int out_size, void* d_ws, size_t ws_size,
                              hipStream_t stream)
{
  const float* hs   = (const float*)d_in[0];
  const float* mask = (const float*)d_in[1];
  const float* qw   = (const float*)d_in[2];
  const float* qb   = (const float*)d_in[3];
  const float* kw   = (const float*)d_in[4];
  const float* kb   = (const float*)d_in[5];
  const float* vw   = (const float*)d_in[6];
  const float* vb   = (const float*)d_in[7];
  const float* ow   = (const float*)d_in[8];
  const float* ob   = (const float*)d_in[9];
  float* out = (float*)d_out;

  char* w = (char*)d_ws;
  int*    flag = (int*)w;
  __bf16* Xb  = (__bf16*)(w + 256);
  __bf16* qwb = Xb  + 4194304;
  __bf16* kwb = qwb + 2097152;
  __bf16* vwb = kwb + 1048576;
  __bf16* owb = vwb + 1048576;
  __bf16* Qo  = owb + 1048576;
  __bf16* Ko  = Qo  + 4194304;
  __bf16* VTo = Ko  + 4194304;
  __bf16* Go  = VTo + 4194304;
  __bf16* At  = Go  + 4194304;

  hipMemsetAsync(flag, 0, sizeof(int), stream);
  cvt_all_kernel<<<2048, 256, 0, stream>>>(hs, qw, kw, vw, ow, Xb, qwb, kwb, vwb, owb,
                                           (const unsigned long long*)mask, flag);
  proj_kernel<<<1024, 256, 0, stream>>>(Xb, qwb, qb, kwb, kb, vwb, vb, Qo, Ko, VTo, Go);
  attn_kernel<<<1024, 256, 0, stream>>>(Qo, Ko, VTo, Go, mask, flag, At);
  oproj_kernel<<<256, 256, 0, stream>>>(At, owb, ob, out);
}

// Round 11
// 148.571 us; speedup vs baseline: 1.0343x; 1.0343x over previous
//
#include <hip/hip_runtime.h>
#include <cstdint>
#include <cstddef>

#define AS1 __attribute__((address_space(1)))
#define AS3 __attribute__((address_space(3)))

typedef __bf16 bf16x8 __attribute__((ext_vector_type(8)));
typedef __bf16 bf16x4 __attribute__((ext_vector_type(4)));
typedef float  f32x4  __attribute__((ext_vector_type(4)));
typedef float  f32x16 __attribute__((ext_vector_type(16)));
typedef unsigned int u32x4 __attribute__((ext_vector_type(4)));

#define MFMA_BF16(a, b, c) __builtin_amdgcn_mfma_f32_16x16x32_bf16((a), (b), (c), 0, 0, 0)
#define MFMA32(a, b, c)    __builtin_amdgcn_mfma_f32_32x32x16_bf16((a), (b), (c), 0, 0, 0)

// async global->LDS, 16B/lane. LDS base wave-uniform; HW adds lane*16. Global addr per-lane.
__device__ __forceinline__ void gload16(const __bf16* g, __bf16* l) {
  __builtin_amdgcn_global_load_lds((AS1 void*)(uintptr_t)g, (AS3 void*)l, 16, 0, 0);
}

__device__ __forceinline__ unsigned int cvtpk_bf16(float lo, float hi) {
  unsigned int r;
  asm("v_cvt_pk_bf16_f32 %0, %1, %2" : "=v"(r) : "v"(lo), "v"(hi));
  return r;
}

// v_permlane32_swap_b32 a, b : a[32:63] <-> b[0:31]
__device__ __forceinline__ void permswap(unsigned int& a, unsigned int& b) {
  asm volatile("v_permlane32_swap_b32 %0, %1" : "+v"(a), "+v"(b));
}

// raw v_exp_f32: computes 2^x
__device__ __forceinline__ float exp2_fast(float x) {
  float r;
  asm("v_exp_f32 %0, %1" : "=v"(r) : "v"(x));
  return r;
}

#define LOG2E 1.4426950408889634f

// ---------------- fp32 -> bf16 conversion (5 tensors) + mask-zero scan, one launch ----------------
__global__ void cvt_all_kernel(
    const float* __restrict__ hs, const float* __restrict__ qw, const float* __restrict__ kw,
    const float* __restrict__ vw, const float* __restrict__ ow,
    __bf16* __restrict__ Xb, __bf16* __restrict__ qwb, __bf16* __restrict__ kwb,
    __bf16* __restrict__ vwb, __bf16* __restrict__ owb,
    const unsigned long long* __restrict__ mask, int* __restrict__ flag)
{
  const int gid = blockIdx.x * blockDim.x + threadIdx.x;
  const int stride = gridDim.x * blockDim.x;
  for (int i = gid; i < 1179648; i += stride) {
    const float* s; __bf16* d; int o;
    if (i < 524288)       { s = hs; d = Xb;  o = i; }
    else if (i < 786432)  { s = qw; d = qwb; o = i - 524288; }
    else if (i < 917504)  { s = kw; d = kwb; o = i - 786432; }
    else if (i < 1048576) { s = vw; d = vwb; o = i - 917504; }
    else                  { s = ow; d = owb; o = i - 1048576; }
    const float4* p = (const float4*)(s + (size_t)o * 8);
    float4 a = p[0], b = p[1];
    bf16x8 v;
    v[0] = (__bf16)a.x; v[1] = (__bf16)a.y; v[2] = (__bf16)a.z; v[3] = (__bf16)a.w;
    v[4] = (__bf16)b.x; v[5] = (__bf16)b.y; v[6] = (__bf16)b.z; v[7] = (__bf16)b.w;
    *(bf16x8*)(d + (size_t)o * 8) = v;
  }
  bool nz = false;
  for (int i = gid; i < 2097152; i += stride) nz |= (mask[i] != 0ull);
  if (nz) atomicOr(flag, 1);
}

// ---------------- fused QGKV projection, 2-phase dbuf, BK=32 (32KB LDS -> 4 blocks/CU) ----------------
__global__ __launch_bounds__(256) void proj_kernel(
    const __bf16* __restrict__ X,
    const __bf16* __restrict__ qw, const float* __restrict__ qb,
    const __bf16* __restrict__ kw, const float* __restrict__ kb,
    const __bf16* __restrict__ vw, const float* __restrict__ vb,
    __bf16* __restrict__ Qo, __bf16* __restrict__ Ko,
    __bf16* __restrict__ VTo, __bf16* __restrict__ Go)
{
  __shared__ __bf16 As[2][128][32];
  __shared__ __bf16 Bs[2][128][32];

  const int bid = blockIdx.x;
  const int r = bid >> 3;
  // ntile fastest within XCD: 4 W-panels (1MB) stay L2-hot, X panel reused by 4 consecutive blocks
  const int ntile = (bid & 7) * 4 + (r & 3);
  const int mtile = r >> 2;
  const int m0 = mtile * 128;
  const int n0 = ntile * 128;

  const __bf16* W; const float* bias; int nb;
  if (n0 < 2048)      { W = qw; bias = qb; nb = n0; }
  else if (n0 < 3072) { W = kw; bias = kb; nb = n0 - 2048; }
  else                { W = vw; bias = vb; nb = n0 - 3072; }

  const int tid = threadIdx.x;
  const int wv = tid >> 6, ln = tid & 63;
  const int wr = wv >> 1, wc = wv & 1;
  const int qr = ln & 15, qg = ln >> 4;
  const int lrow = ln >> 2, lcol = (ln & 3) * 8;   // staging: 16 rows x 32 cols per wave-instr

  f32x4 acc[4][4];
#pragma unroll
  for (int m = 0; m < 4; ++m)
#pragma unroll
    for (int n = 0; n < 4; ++n) acc[m][n] = 0.f;

  __bf16 (*Asc)[32] = As[0], (*Asn)[32] = As[1];
  __bf16 (*Bsc)[32] = Bs[0], (*Bsn)[32] = Bs[1];

  // prologue: stage k-tile 0
#pragma unroll
  for (int i = 0; i < 2; ++i) {
    const int rb = i * 64 + wv * 16;
    gload16(X + (size_t)(m0 + rb + lrow) * 1024 + lcol, &Asc[rb][0]);
    gload16(W + (size_t)(nb + rb + lrow) * 1024 + lcol, &Bsc[rb][0]);
  }
  __syncthreads();

  for (int t = 0; t < 32; ++t) {
    if (t < 31) {
      const int k0 = (t + 1) * 32;
#pragma unroll
      for (int i = 0; i < 2; ++i) {
        const int rb = i * 64 + wv * 16;
        gload16(X + (size_t)(m0 + rb + lrow) * 1024 + k0 + lcol, &Asn[rb][0]);
        gload16(W + (size_t)(nb + rb + lrow) * 1024 + k0 + lcol, &Bsn[rb][0]);
      }
    }
    {
      bf16x8 af[4], bfv[4];
#pragma unroll
      for (int m = 0; m < 4; ++m) af[m] = *(const bf16x8*)&Asc[wr * 64 + m * 16 + qr][qg * 8];
#pragma unroll
      for (int n = 0; n < 4; ++n) bfv[n] = *(const bf16x8*)&Bsc[wc * 64 + n * 16 + qr][qg * 8];
#pragma unroll
      for (int m = 0; m < 4; ++m)
#pragma unroll
        for (int n = 0; n < 4; ++n) acc[m][n] = MFMA_BF16(af[m], bfv[n], acc[m][n]);
    }
    __syncthreads();   // drains vmcnt (next tile staged) + orders LDS reuse
    __bf16 (*ta)[32] = Asc; Asc = Asn; Asn = ta;
    __bf16 (*tb)[32] = Bsc; Bsc = Bsn; Bsn = tb;
  }

  // epilogue: C/D layout col=lane&15, row=(lane>>4)*4+reg
#pragma unroll
  for (int m = 0; m < 4; ++m) {
    const int gm0 = m0 + wr * 64 + m * 16 + qg * 4;
    const int b = gm0 >> 11;
    const int s = gm0 & 2047;
#pragma unroll
    for (int n = 0; n < 4; ++n) {
      const int nl = wc * 64 + n * 16 + qr;
      const float bb = bias[nb + nl];
      if (n0 < 1024) {            // Q -> [b,h,s,d], pre-scaled by log2e/sqrt(d) (exp2-domain softmax)
        const int col = n0 + nl, hh = col >> 6, dd = col & 63;
        __bf16* dst = Qo + ((size_t)((b << 4) + hh)) * 131072 + (size_t)s * 64 + dd;
#pragma unroll
        for (int rr = 0; rr < 4; ++rr) dst[(size_t)rr * 64] = (__bf16)((acc[m][n][rr] + bb) * (0.125f * LOG2E));
      } else if (n0 < 2048) {     // gate -> sigmoid -> [token, h*64+d]
        const int j = n0 - 1024 + nl;
        __bf16* dst = Go + (size_t)gm0 * 1024 + j;
#pragma unroll
        for (int rr = 0; rr < 4; ++rr) {
          const float v = acc[m][n][rr] + bb;
          dst[(size_t)rr * 1024] = (__bf16)(1.f / (1.f + __expf(-v)));
        }
      } else if (n0 < 3072) {     // K -> [b,h,s,d]
        const int j = n0 - 2048 + nl, hh = j >> 6, dd = j & 63;
        __bf16* dst = Ko + ((size_t)((b << 4) + hh)) * 131072 + (size_t)s * 64 + dd;
#pragma unroll
        for (int rr = 0; rr < 4; ++rr) dst[(size_t)rr * 64] = (__bf16)(acc[m][n][rr] + bb);
      } else {                    // V -> transposed [b,h,d,s]
        const int j = n0 - 3072 + nl, hh = j >> 6, dd = j & 63;
        bf16x4 pv;
#pragma unroll
        for (int rr = 0; rr < 4; ++rr) pv[rr] = (__bf16)(acc[m][n][rr] + bb);
        *(bf16x4*)(VTo + ((size_t)((b << 4) + hh)) * 131072 + (size_t)dd * 2048 + s) = pv;
      }
    }
  }
}

// ---------------- flash attention (round-9 structure): dbuf LDS-staged K/V, swapped-QK^T, exp2 softmax ----------------
// Block = 4 waves (256 thr) = one head, 128 q rows; wave w owns q0+w*32.
// K/V tiles (64 kv x 64 d) staged as [32 rows][256B] with 16B-granule XOR swizzle.
// Scores (mfma(K,Q)): lane holds S[kv=(r&3)+8(r>>2)+4hi][q=lq], log2 domain (Q pre-scaled).
// Softmax: defer-max (THR=8), exp2, per-lane partial lrun. PV: lane holds O[d][q=lq].
__global__ __launch_bounds__(256, 2) void attn_kernel(
    const __bf16* __restrict__ Qb, const __bf16* __restrict__ Kb,
    const __bf16* __restrict__ VT, const __bf16* __restrict__ G,
    const float* __restrict__ mask, const int* __restrict__ flag,
    __bf16* __restrict__ attn)
{
  __shared__ __bf16 Ksh[2][32][128];  // 2 x 8KB, swizzled
  __shared__ __bf16 Vsh[2][32][128];

  const int bid = blockIdx.x;    // 512 = 8 xcd * (4 heads * 16 qblocks)
  const int y = bid >> 3;        // 0..63
  const int hl = (bid & 7) * 4 + (y >> 4);  // 4 heads per XCD
  const int tid = threadIdx.x;
  const int w = tid >> 6;        // wave 0..3
  const int ln = tid & 63;
  const int lq = ln & 31;
  const int hi = ln >> 5;
  const int q0 = (y & 15) * 128 + w * 32;
  const int b = hl >> 4, h = hl & 15;

  const __bf16* Qh = Qb + (size_t)hl * 131072;
  const __bf16* Kh = Kb + (size_t)hl * 131072;
  const __bf16* Vh = VT + (size_t)hl * 131072;

  // staging source offsets (elements within head), chunk-invariant parts
  int kco[2], vco[2], ldst[2];
#pragma unroll
  for (int i = 0; i < 2; ++i) {
    const int prow = w * 8 + i * 4 + (ln >> 4);  // physical LDS row 0..31
    const int bphys = (ln & 15) * 16;
    const int blog = bphys ^ ((prow & 15) << 4);
    const int half = blog >> 7;             // K: kv-half | V: d-half
    const int col = (blog & 127) >> 1;      // K: d | V: kv-local
    kco[i] = (half * 32 + prow) * 64 + col;
    vco[i] = (half * 32 + prow) * 2048 + col;
    ldst[i] = (w * 8 + i * 4) * 256;        // byte offset of instruction's LDS slab
  }
  const int swz = (lq & 15) << 4;
  const int krow = lq * 256;

  // Q (pre-scaled to log2 domain): frag ks: Q[q0+lq][16ks+8hi+0..7]
  bf16x8 qf[4];
#pragma unroll
  for (int ks = 0; ks < 4; ++ks)
    qf[ks] = *(const bf16x8*)(Qh + (size_t)(q0 + lq) * 64 + ks * 16 + hi * 8);

  f32x16 o0, o1;
#pragma unroll
  for (int i = 0; i < 16; ++i) { o0[i] = 0.f; o1[i] = 0.f; }
  float mrun = -1e30f, lrun = 0.f;

  const bool um = (*flag) != 0;

  char* Kc = (char*)&Ksh[0][0][0];  char* Kn = (char*)&Ksh[1][0][0];
  char* Vc = (char*)&Vsh[0][0][0];  char* Vn = (char*)&Vsh[1][0][0];

  // prologue: stage chunk 0
#pragma unroll
  for (int i = 0; i < 2; ++i) {
    gload16(Kh + kco[i], (__bf16*)(Kc + ldst[i]));
    gload16(Vh + vco[i], (__bf16*)(Vc + ldst[i]));
  }
  __syncthreads();

  for (int c = 0; c < 32; ++c) {
    const int kv0 = c * 64;
    if (c < 31) {
      const int kvn = kv0 + 64;
#pragma unroll
      for (int i = 0; i < 2; ++i) {
        gload16(Kh + kvn * 64 + kco[i], (__bf16*)(Kn + ldst[i]));
        gload16(Vh + kvn + vco[i],      (__bf16*)(Vn + ldst[i]));
      }
    }

#pragma unroll
    for (int s32 = 0; s32 < 2; ++s32) {
      bf16x8 kf[4];
#pragma unroll
      for (int ks = 0; ks < 4; ++ks)
        kf[ks] = *(const bf16x8*)(Kc + krow + ((s32 * 128 + ks * 32 + hi * 16) ^ swz));

      f32x16 s;
#pragma unroll
      for (int i = 0; i < 16; ++i) s[i] = 0.f;
      __builtin_amdgcn_s_setprio(1);
#pragma unroll
      for (int ks = 0; ks < 4; ++ks) s = MFMA32(kf[ks], qf[ks], s);
      __builtin_amdgcn_s_setprio(0);

      float p[16];
      if (um) {
        const size_t mrow = (size_t)(q0 + lq) * 2048 + kv0 + s32 * 32;
#pragma unroll
        for (int i = 0; i < 16; ++i)
          p[i] = s[i] + mask[mrow + (i & 3) + 8 * (i >> 2) + 4 * hi] * LOG2E;
      } else {
#pragma unroll
        for (int i = 0; i < 16; ++i) p[i] = s[i];
      }

      // row max over 32 kv: nested-triple fmax tree + 1 cross-half shuffle
      float t = fmaxf(fmaxf(p[0], p[1]), p[2]);
      t = fmaxf(fmaxf(t, p[3]), p[4]);
      t = fmaxf(fmaxf(t, p[5]), p[6]);
      t = fmaxf(fmaxf(t, p[7]), p[8]);
      t = fmaxf(fmaxf(t, p[9]), p[10]);
      t = fmaxf(fmaxf(t, p[11]), p[12]);
      t = fmaxf(fmaxf(t, p[13]), p[14]);
      t = fmaxf(t, p[15]);
      t = fmaxf(t, __shfl_xor(t, 32));

      // defer-max: rescale only when running max grows by > 8 (rare; execz-skipped)
      if (t > mrun + 8.f) {
        const float al = exp2_fast(mrun - t);
        mrun = t;
        lrun *= al;
#pragma unroll
        for (int i = 0; i < 16; ++i) { o0[i] *= al; o1[i] *= al; }
      }

      float ps = 0.f;
#pragma unroll
      for (int i = 0; i < 16; ++i) { p[i] = exp2_fast(p[i] - mrun); ps += p[i]; }
      lrun += ps;   // per-lane partial; cross-half combine at end

      // pack P into B-frag layout: pa[ks] holds P[q=lq][16ks + 8hi + 0..7]
      bf16x8 pa[2];
#pragma unroll
      for (int ks = 0; ks < 2; ++ks) {
        unsigned int c0 = cvtpk_bf16(p[8 * ks + 0], p[8 * ks + 1]);
        unsigned int c1 = cvtpk_bf16(p[8 * ks + 2], p[8 * ks + 3]);
        unsigned int c2 = cvtpk_bf16(p[8 * ks + 4], p[8 * ks + 5]);
        unsigned int c3 = cvtpk_bf16(p[8 * ks + 6], p[8 * ks + 7]);
        permswap(c0, c2);
        permswap(c1, c3);
        u32x4 wv; wv.x = c0; wv.y = c1; wv.z = c2; wv.w = c3;
        pa[ks] = __builtin_bit_cast(bf16x8, wv);
      }

      // PV from swizzled Vsh: V^T rows = d, cols = kv
      __builtin_amdgcn_s_setprio(1);
#pragma unroll
      for (int ks = 0; ks < 2; ++ks) {
        const int kvb = s32 * 64 + ks * 32 + hi * 16;
        bf16x8 v0 = *(const bf16x8*)(Vc + krow + ((0 + kvb) ^ swz));
        bf16x8 v1 = *(const bf16x8*)(Vc + krow + ((128 + kvb) ^ swz));
        o0 = MFMA32(v0, pa[ks], o0);
        o1 = MFMA32(v1, pa[ks], o1);
      }
      __builtin_amdgcn_s_setprio(0);
    }
    __syncthreads();   // drains vmcnt (next chunk staged) + orders LDS reuse
    char* tk = Kc; Kc = Kn; Kn = tk;
    char* tv = Vc; Vc = Vn; Vn = tv;
  }

  // combine per-lane lrun across the kv-half pair, then normalize+gate+store
  lrun += __shfl_xor(lrun, 32);
  const float inv = 1.f / lrun;
  const size_t base = ((size_t)(b * 2048 + q0 + lq)) * 1024 + h * 64;
#pragma unroll
  for (int half = 0; half < 2; ++half) {
#pragma unroll
    for (int g = 0; g < 4; ++g) {
      const int d0 = half * 32 + g * 8 + hi * 4;
      bf16x4 g4 = *(const bf16x4*)(G + base + d0);
      bf16x4 r4;
#pragma unroll
      for (int j = 0; j < 4; ++j) {
        const float ov = half ? o1[g * 4 + j] : o0[g * 4 + j];
        r4[j] = (__bf16)(ov * inv * (float)g4[j]);
      }
      *(bf16x4*)(attn + base + d0) = r4;
    }
  }
}

// ---------------- O projection (bf16 in, fp32 out), 2-phase dbuf ----------------
__global__ __launch_bounds__(256) void oproj_kernel(
    const __bf16* __restrict__ A, const __bf16* __restrict__ ow,
    const float* __restrict__ ob, float* __restrict__ C)
{
  __shared__ __bf16 As[2][128][64];
  __shared__ __bf16 Bs[2][128][64];
  const int bid = blockIdx.x;
  const int ntile = bid & 7;
  const int mtile = bid >> 3;
  const int m0 = mtile * 128, n0 = ntile * 128;

  const int tid = threadIdx.x;
  const int wv = tid >> 6, ln = tid & 63;
  const int wr = wv >> 1, wc = wv & 1;
  const int qr = ln & 15, qg = ln >> 4;
  const int lrow = ln >> 3, lcol = (ln & 7) * 8;

  f32x4 acc[4][4];
#pragma unroll
  for (int m = 0; m < 4; ++m)
#pragma unroll
    for (int n = 0; n < 4; ++n) acc[m][n] = 0.f;

  __bf16 (*Asc)[64] = As[0], (*Asn)[64] = As[1];
  __bf16 (*Bsc)[64] = Bs[0], (*Bsn)[64] = Bs[1];

#pragma unroll
  for (int i = 0; i < 4; ++i) {
    const int rb = i * 32 + wv * 8;
    gload16(A  + (size_t)(m0 + rb + lrow) * 1024 + lcol, &Asc[rb][0]);
    gload16(ow + (size_t)(n0 + rb + lrow) * 1024 + lcol, &Bsc[rb][0]);
  }
  __syncthreads();

  for (int t = 0; t < 16; ++t) {
    if (t < 15) {
      const int k0 = (t + 1) * 64;
#pragma unroll
      for (int i = 0; i < 4; ++i) {
        const int rb = i * 32 + wv * 8;
        gload16(A  + (size_t)(m0 + rb + lrow) * 1024 + k0 + lcol, &Asn[rb][0]);
        gload16(ow + (size_t)(n0 + rb + lrow) * 1024 + k0 + lcol, &Bsn[rb][0]);
      }
    }
#pragma unroll
    for (int kk = 0; kk < 2; ++kk) {
      bf16x8 af[4], bfv[4];
#pragma unroll
      for (int m = 0; m < 4; ++m) af[m] = *(const bf16x8*)&Asc[wr * 64 + m * 16 + qr][kk * 32 + qg * 8];
#pragma unroll
      for (int n = 0; n < 4; ++n) bfv[n] = *(const bf16x8*)&Bsc[wc * 64 + n * 16 + qr][kk * 32 + qg * 8];
#pragma unroll
      for (int m = 0; m < 4; ++m)
#pragma unroll
        for (int n = 0; n < 4; ++n) acc[m][n] = MFMA_BF16(af[m], bfv[n], acc[m][n]);
    }
    __syncthreads();
    __bf16 (*ta)[64] = Asc; Asc = Asn; Asn = ta;
    __bf16 (*tb)[64] = Bsc; Bsc = Bsn; Bsn = tb;
  }

#pragma unroll
  for (int m = 0; m < 4; ++m) {
    const int gm0 = m0 + wr * 64 + m * 16 + qg * 4;
#pragma unroll
    for (int n = 0; n < 4; ++n) {
      const int gn = n0 + wc * 64 + n * 16 + qr;
      const float bb = ob[gn];
      float* dst = C + (size_t)gm0 * 1024 + gn;
#pragma unroll
      for (int rr = 0; rr < 4; ++rr) dst[(size_t)rr * 1024] = acc[m][n][rr] + bb;
    }
  }
}

extern "C" void kernel_launch(void* const* d_in, const int* in_sizes, int n_in,
                              void* d_out, int out_size, void* d_ws, size_t ws_size,
                              hipStream_t stream)
{
  const float* hs   = (const float*)d_in[0];
  const float* mask = (const float*)d_in[1];
  const float* qw   = (const float*)d_in[2];
  const float* qb   = (const float*)d_in[3];
  const float* kw   = (const float*)d_in[4];
  const float* kb   = (const float*)d_in[5];
  const float* vw   = (const float*)d_in[6];
  const float* vb   = (const float*)d_in[7];
  const float* ow   = (const float*)d_in[8];
  const float* ob   = (const float*)d_in[9];
  float* out = (float*)d_out;

  char* w = (char*)d_ws;
  int*    flag = (int*)w;
  __bf16* Xb  = (__bf16*)(w + 256);
  __bf16* qwb = Xb  + 4194304;
  __bf16* kwb = qwb + 2097152;
  __bf16* vwb = kwb + 1048576;
  __bf16* owb = vwb + 1048576;
  __bf16* Qo  = owb + 1048576;
  __bf16* Ko  = Qo  + 4194304;
  __bf16* VTo = Ko  + 4194304;
  __bf16* Go  = VTo + 4194304;
  __bf16* At  = Go  + 4194304;

  hipMemsetAsync(flag, 0, sizeof(int), stream);
  cvt_all_kernel<<<2048, 256, 0, stream>>>(hs, qw, kw, vw, ow, Xb, qwb, kwb, vwb, owb,
                                           (const unsigned long long*)mask, flag);
  proj_kernel<<<1024, 256, 0, stream>>>(Xb, qwb, qb, kwb, kb, vwb, vb, Qo, Ko, VTo, Go);
  attn_kernel<<<512, 256, 0, stream>>>(Qo, Ko, VTo, Go, mask, flag, At);
  oproj_kernel<<<256, 256, 0, stream>>>(At, owb, ob, out);
}

// Round 12
// 137.169 us; speedup vs baseline: 1.1203x; 1.0831x over previous
//
#include <hip/hip_runtime.h>
#include <cstdint>
#include <cstddef>

#define AS1 __attribute__((address_space(1)))
#define AS3 __attribute__((address_space(3)))

typedef __bf16 bf16x8 __attribute__((ext_vector_type(8)));
typedef __bf16 bf16x4 __attribute__((ext_vector_type(4)));
typedef float  f32x4  __attribute__((ext_vector_type(4)));
typedef float  f32x16 __attribute__((ext_vector_type(16)));
typedef unsigned int u32x4 __attribute__((ext_vector_type(4)));

#define MFMA_BF16(a, b, c) __builtin_amdgcn_mfma_f32_16x16x32_bf16((a), (b), (c), 0, 0, 0)
#define MFMA32(a, b, c)    __builtin_amdgcn_mfma_f32_32x32x16_bf16((a), (b), (c), 0, 0, 0)

// async global->LDS, 16B/lane. LDS base wave-uniform; HW adds lane*16. Global addr per-lane.
__device__ __forceinline__ void gload16(const __bf16* g, __bf16* l) {
  __builtin_amdgcn_global_load_lds((AS1 void*)(uintptr_t)g, (AS3 void*)l, 16, 0, 0);
}

__device__ __forceinline__ unsigned int cvtpk_bf16(float lo, float hi) {
  unsigned int r;
  asm("v_cvt_pk_bf16_f32 %0, %1, %2" : "=v"(r) : "v"(lo), "v"(hi));
  return r;
}

// v_permlane32_swap_b32 a, b : a[32:63] <-> b[0:31]
__device__ __forceinline__ void permswap(unsigned int& a, unsigned int& b) {
  asm volatile("v_permlane32_swap_b32 %0, %1" : "+v"(a), "+v"(b));
}

// raw v_exp_f32: computes 2^x
__device__ __forceinline__ float exp2_fast(float x) {
  float r;
  asm("v_exp_f32 %0, %1" : "=v"(r) : "v"(x));
  return r;
}

#define LOG2E 1.4426950408889634f

// ---------------- fp32 -> bf16 conversion (5 tensors) + mask-zero scan, one launch ----------------
__global__ void cvt_all_kernel(
    const float* __restrict__ hs, const float* __restrict__ qw, const float* __restrict__ kw,
    const float* __restrict__ vw, const float* __restrict__ ow,
    __bf16* __restrict__ Xb, __bf16* __restrict__ qwb, __bf16* __restrict__ kwb,
    __bf16* __restrict__ vwb, __bf16* __restrict__ owb,
    const unsigned long long* __restrict__ mask, int* __restrict__ flag)
{
  const int gid = blockIdx.x * blockDim.x + threadIdx.x;
  const int stride = gridDim.x * blockDim.x;
  for (int i = gid; i < 1179648; i += stride) {
    const float* s; __bf16* d; int o;
    if (i < 524288)       { s = hs; d = Xb;  o = i; }
    else if (i < 786432)  { s = qw; d = qwb; o = i - 524288; }
    else if (i < 917504)  { s = kw; d = kwb; o = i - 786432; }
    else if (i < 1048576) { s = vw; d = vwb; o = i - 917504; }
    else                  { s = ow; d = owb; o = i - 1048576; }
    const float4* p = (const float4*)(s + (size_t)o * 8);
    float4 a = p[0], b = p[1];
    bf16x8 v;
    v[0] = (__bf16)a.x; v[1] = (__bf16)a.y; v[2] = (__bf16)a.z; v[3] = (__bf16)a.w;
    v[4] = (__bf16)b.x; v[5] = (__bf16)b.y; v[6] = (__bf16)b.z; v[7] = (__bf16)b.w;
    *(bf16x8*)(d + (size_t)o * 8) = v;
  }
  bool nz = false;
  for (int i = gid; i < 2097152; i += stride) nz |= (mask[i] != 0ull);
  if (nz) atomicOr(flag, 1);
}

// ---------------- fused QGKV projection: 256x256 tile, BK=64, 8-phase counted-vmcnt pipeline ----------------
// 8 waves (2M x 4N), per-wave 128x64 out, acc[8][4] f32x4. LDS 128KB dynamic:
// A[2][256][64] | B[2][256][64], 16B-granule XOR swizzle (c ^= (row&7)<<4), staged via
// gload16 with pre-swizzled global source. Halves are quadrant-aligned interleaved row sets:
// A.H0 = mh0 rows {0-63,128-191}, A.H1 = mh1 rows; B.H0 = nh0 rows {x*64+[0,32)}, B.H1 = nh1.
// Phase schedule (tile a=2it in buf0 P1-4, tile b in buf1 P5-8; stages 2 tiles ahead):
//   P1 ld A0B0(b0), st b1.A1 | P2 ld B1(b0), st b0.A0 | P3 ld A1(b0), st b0.B0
//   P4 st b0.B1 +vmcnt(6)    | P5 ld A0B0(b1), st b0.A1 | P6 ld B1(b1), st b1.A0
//   P7 ld A1(b1), st b1.B0   | P8 st b1.B1 +vmcnt(6)
__global__ __launch_bounds__(512, 2) void proj_kernel(
    const __bf16* __restrict__ X,
    const __bf16* __restrict__ qw, const float* __restrict__ qb,
    const __bf16* __restrict__ kw, const float* __restrict__ kb,
    const __bf16* __restrict__ vw, const float* __restrict__ vb,
    __bf16* __restrict__ Qo, __bf16* __restrict__ Ko,
    __bf16* __restrict__ VTo, __bf16* __restrict__ Go)
{
  extern __shared__ char smem[];   // [0,64K): A bufs; [64K,128K): B bufs

  const int bid = blockIdx.x;      // 256 blocks, 1 per CU
  const int jj = bid >> 3;
  const int ntile = (bid & 7) * 2 + (jj >> 4);   // 2 ntiles per XCD -> B panels L2-hot
  const int mtile = jj & 15;
  const int m0 = mtile * 256, n0 = ntile * 256;

  const __bf16* W; const float* bias; int nb;
  if (n0 < 2048)      { W = qw; bias = qb; nb = n0; }
  else if (n0 < 3072) { W = kw; bias = kb; nb = n0 - 2048; }
  else                { W = vw; bias = vb; nb = n0 - 3072; }

  const int tid = threadIdx.x;
  const int wid = tid >> 6;        // 0..7
  const int wr = wid >> 2;         // 0..1 (M)
  const int wc = wid & 3;          // 0..3 (N)
  const int ln = tid & 63;
  const int qr = ln & 15, qg = ln >> 4;

  // staging lane constants: lane covers physical granule (ln&7) of row +(ln>>3); the data
  // there is logical granule (ln&7)^(row&7), row&7 == ln>>3 for 8-aligned row bases.
  const int srow = ln >> 3;                    // 0..7
  const int sgran = ((ln & 7) ^ srow) * 8;     // source col element base

// stage A half: rows half*64 + i*128 + wid*8 .. +8
#define SA(buf, half, kt) do { \
  _Pragma("unroll") for (int i_ = 0; i_ < 2; ++i_) { \
    const int r0_ = (half) * 64 + i_ * 128 + wid * 8; \
    gload16(X + (size_t)(m0 + r0_ + srow) * 1024 + (kt) * 64 + sgran, \
            (__bf16*)(smem + (buf) * 32768 + r0_ * 128)); \
  } } while (0)

// stage B half: group g = wid + i*8 -> rows (g>>2)*64 + half*32 + (g&3)*8 .. +8
#define SB(buf, half, kt) do { \
  _Pragma("unroll") for (int i_ = 0; i_ < 2; ++i_) { \
    const int g_ = wid + i_ * 8; \
    const int r0_ = (g_ >> 2) * 64 + (half) * 32 + (g_ & 3) * 8; \
    gload16(W + (size_t)(nb + r0_ + srow) * 1024 + (kt) * 64 + sgran, \
            (__bf16*)(smem + 65536 + (buf) * 32768 + r0_ * 128)); \
  } } while (0)

#define LDA(buf, mh, mi, kk) (*(const bf16x8*)(smem + (buf) * 32768 + \
    (wr * 128 + (mh) * 64 + (mi) * 16 + qr) * 128 + (((kk) * 64 + qg * 16) ^ ((qr & 7) << 4))))
#define LDB(buf, nh, ni, kk) (*(const bf16x8*)(smem + 65536 + (buf) * 32768 + \
    (wc * 64 + (nh) * 32 + (ni) * 16 + qr) * 128 + (((kk) * 64 + qg * 16) ^ ((qr & 7) << 4))))

  f32x4 acc[8][4];
#pragma unroll
  for (int m = 0; m < 8; ++m)
#pragma unroll
    for (int n = 0; n < 4; ++n) acc[m][n] = 0.f;

  bf16x8 af[4][2], b0f[2][2], b1f[2][2];

#define QUAD(mh, nh, BF) do { \
  asm volatile("s_waitcnt lgkmcnt(0)"); \
  __builtin_amdgcn_sched_barrier(0); \
  __builtin_amdgcn_s_setprio(1); \
  _Pragma("unroll") for (int mi_ = 0; mi_ < 4; ++mi_) \
    _Pragma("unroll") for (int ni_ = 0; ni_ < 2; ++ni_) { \
      acc[(mh)*4+mi_][(nh)*2+ni_] = MFMA_BF16(af[mi_][0], BF[ni_][0], acc[(mh)*4+mi_][(nh)*2+ni_]); \
      acc[(mh)*4+mi_][(nh)*2+ni_] = MFMA_BF16(af[mi_][1], BF[ni_][1], acc[(mh)*4+mi_][(nh)*2+ni_]); \
    } \
  __builtin_amdgcn_s_setprio(0); \
} while (0)

#define BAR() __builtin_amdgcn_s_barrier()

  // prologue: tile0 -> buf0 (4 halves), tile1 -> buf1 (A0,B0,B1); A1 of tile1 staged at P1
  SA(0, 0, 0); SA(0, 1, 0); SB(0, 0, 0); SB(0, 1, 0);
  SA(1, 0, 1); SB(1, 0, 1); SB(1, 1, 1);
  asm volatile("s_waitcnt vmcnt(6)");   // tile0's 8 loads landed
  BAR();

  for (int it = 0; it < 8; ++it) {
    const int tb = 2 * it + 1;
    const int tc = (2 * it + 2 < 16) ? 2 * it + 2 : 15;  // clamped tail restage (data unused)
    const int td = (2 * it + 3 < 16) ? 2 * it + 3 : 15;

    // ---- tile a (buf0) ----
    // P1
#pragma unroll
    for (int mi = 0; mi < 4; ++mi) { af[mi][0] = LDA(0, 0, mi, 0); af[mi][1] = LDA(0, 0, mi, 1); }
#pragma unroll
    for (int ni = 0; ni < 2; ++ni) { b0f[ni][0] = LDB(0, 0, ni, 0); b0f[ni][1] = LDB(0, 0, ni, 1); }
    SA(1, 1, tb);
    BAR();
    QUAD(0, 0, b0f);
    BAR();
    // P2
#pragma unroll
    for (int ni = 0; ni < 2; ++ni) { b1f[ni][0] = LDB(0, 1, ni, 0); b1f[ni][1] = LDB(0, 1, ni, 1); }
    SA(0, 0, tc);
    BAR();
    QUAD(0, 1, b1f);
    BAR();
    // P3
#pragma unroll
    for (int mi = 0; mi < 4; ++mi) { af[mi][0] = LDA(0, 1, mi, 0); af[mi][1] = LDA(0, 1, mi, 1); }
    SB(0, 0, tc);
    BAR();
    QUAD(1, 1, b1f);
    BAR();
    // P4
    SB(0, 1, tc);
    asm volatile("s_waitcnt vmcnt(6)");
    BAR();
    QUAD(1, 0, b0f);
    BAR();

    // ---- tile b (buf1) ----
    // P5
#pragma unroll
    for (int mi = 0; mi < 4; ++mi) { af[mi][0] = LDA(1, 0, mi, 0); af[mi][1] = LDA(1, 0, mi, 1); }
#pragma unroll
    for (int ni = 0; ni < 2; ++ni) { b0f[ni][0] = LDB(1, 0, ni, 0); b0f[ni][1] = LDB(1, 0, ni, 1); }
    SA(0, 1, tc);
    BAR();
    QUAD(0, 0, b0f);
    BAR();
    // P6
#pragma unroll
    for (int ni = 0; ni < 2; ++ni) { b1f[ni][0] = LDB(1, 1, ni, 0); b1f[ni][1] = LDB(1, 1, ni, 1); }
    SA(1, 0, td);
    BAR();
    QUAD(0, 1, b1f);
    BAR();
    // P7
#pragma unroll
    for (int mi = 0; mi < 4; ++mi) { af[mi][0] = LDA(1, 1, mi, 0); af[mi][1] = LDA(1, 1, mi, 1); }
    SB(1, 0, td);
    BAR();
    QUAD(1, 1, b1f);
    BAR();
    // P8
    SB(1, 1, td);
    asm volatile("s_waitcnt vmcnt(6)");
    BAR();
    QUAD(1, 0, b0f);
    BAR();
  }

  // epilogue: C/D layout col=lane&15, row=(lane>>4)*4+reg
#pragma unroll
  for (int mi = 0; mi < 8; ++mi) {
    const int gm0 = m0 + wr * 128 + mi * 16 + qg * 4;
    const int b = gm0 >> 11;
    const int s = gm0 & 2047;
#pragma unroll
    for (int ni = 0; ni < 4; ++ni) {
      const int nl = wc * 64 + ni * 16 + qr;     // 0..255 within tile
      const float bb = bias[nb + nl];
      if (n0 < 1024) {            // Q -> [b,h,s,d], pre-scaled by log2e/sqrt(d)
        const int col = n0 + nl, hh = col >> 6, dd = col & 63;
        __bf16* dst = Qo + ((size_t)((b << 4) + hh)) * 131072 + (size_t)s * 64 + dd;
#pragma unroll
        for (int rr = 0; rr < 4; ++rr) dst[(size_t)rr * 64] = (__bf16)((acc[mi][ni][rr] + bb) * (0.125f * LOG2E));
      } else if (n0 < 2048) {     // gate -> sigmoid -> [token, h*64+d]
        const int j = n0 - 1024 + nl;
        __bf16* dst = Go + (size_t)gm0 * 1024 + j;
#pragma unroll
        for (int rr = 0; rr < 4; ++rr) {
          const float v = acc[mi][ni][rr] + bb;
          dst[(size_t)rr * 1024] = (__bf16)(1.f / (1.f + __expf(-v)));
        }
      } else if (n0 < 3072) {     // K -> [b,h,s,d]
        const int j = n0 - 2048 + nl, hh = j >> 6, dd = j & 63;
        __bf16* dst = Ko + ((size_t)((b << 4) + hh)) * 131072 + (size_t)s * 64 + dd;
#pragma unroll
        for (int rr = 0; rr < 4; ++rr) dst[(size_t)rr * 64] = (__bf16)(acc[mi][ni][rr] + bb);
      } else {                    // V -> transposed [b,h,d,s]
        const int j = n0 - 3072 + nl, hh = j >> 6, dd = j & 63;
        bf16x4 pv;
#pragma unroll
        for (int rr = 0; rr < 4; ++rr) pv[rr] = (__bf16)(acc[mi][ni][rr] + bb);
        *(bf16x4*)(VTo + ((size_t)((b << 4) + hh)) * 131072 + (size_t)dd * 2048 + s) = pv;
      }
    }
  }
#undef SA
#undef SB
#undef LDA
#undef LDB
#undef QUAD
#undef BAR
}

// ---------------- flash attention (round-9 structure): dbuf LDS-staged K/V, swapped-QK^T, exp2 softmax ----------------
__global__ __launch_bounds__(256, 2) void attn_kernel(
    const __bf16* __restrict__ Qb, const __bf16* __restrict__ Kb,
    const __bf16* __restrict__ VT, const __bf16* __restrict__ G,
    const float* __restrict__ mask, const int* __restrict__ flag,
    __bf16* __restrict__ attn)
{
  __shared__ __bf16 Ksh[2][32][128];  // 2 x 8KB, swizzled
  __shared__ __bf16 Vsh[2][32][128];

  const int bid = blockIdx.x;    // 512 = 8 xcd * (4 heads * 16 qblocks)
  const int y = bid >> 3;        // 0..63
  const int hl = (bid & 7) * 4 + (y >> 4);  // 4 heads per XCD
  const int tid = threadIdx.x;
  const int w = tid >> 6;        // wave 0..3
  const int ln = tid & 63;
  const int lq = ln & 31;
  const int hi = ln >> 5;
  const int q0 = (y & 15) * 128 + w * 32;
  const int b = hl >> 4, h = hl & 15;

  const __bf16* Qh = Qb + (size_t)hl * 131072;
  const __bf16* Kh = Kb + (size_t)hl * 131072;
  const __bf16* Vh = VT + (size_t)hl * 131072;

  int kco[2], vco[2], ldst[2];
#pragma unroll
  for (int i = 0; i < 2; ++i) {
    const int prow = w * 8 + i * 4 + (ln >> 4);
    const int bphys = (ln & 15) * 16;
    const int blog = bphys ^ ((prow & 15) << 4);
    const int half = blog >> 7;
    const int col = (blog & 127) >> 1;
    kco[i] = (half * 32 + prow) * 64 + col;
    vco[i] = (half * 32 + prow) * 2048 + col;
    ldst[i] = (w * 8 + i * 4) * 256;
  }
  const int swz = (lq & 15) << 4;
  const int krow = lq * 256;

  bf16x8 qf[4];
#pragma unroll
  for (int ks = 0; ks < 4; ++ks)
    qf[ks] = *(const bf16x8*)(Qh + (size_t)(q0 + lq) * 64 + ks * 16 + hi * 8);

  f32x16 o0, o1;
#pragma unroll
  for (int i = 0; i < 16; ++i) { o0[i] = 0.f; o1[i] = 0.f; }
  float mrun = -1e30f, lrun = 0.f;

  const bool um = (*flag) != 0;

  char* Kc = (char*)&Ksh[0][0][0];  char* Kn = (char*)&Ksh[1][0][0];
  char* Vc = (char*)&Vsh[0][0][0];  char* Vn = (char*)&Vsh[1][0][0];

#pragma unroll
  for (int i = 0; i < 2; ++i) {
    gload16(Kh + kco[i], (__bf16*)(Kc + ldst[i]));
    gload16(Vh + vco[i], (__bf16*)(Vc + ldst[i]));
  }
  __syncthreads();

  for (int c = 0; c < 32; ++c) {
    const int kv0 = c * 64;
    if (c < 31) {
      const int kvn = kv0 + 64;
#pragma unroll
      for (int i = 0; i < 2; ++i) {
        gload16(Kh + kvn * 64 + kco[i], (__bf16*)(Kn + ldst[i]));
        gload16(Vh + kvn + vco[i],      (__bf16*)(Vn + ldst[i]));
      }
    }

#pragma unroll
    for (int s32 = 0; s32 < 2; ++s32) {
      bf16x8 kf[4];
#pragma unroll
      for (int ks = 0; ks < 4; ++ks)
        kf[ks] = *(const bf16x8*)(Kc + krow + ((s32 * 128 + ks * 32 + hi * 16) ^ swz));

      f32x16 s;
#pragma unroll
      for (int i = 0; i < 16; ++i) s[i] = 0.f;
      __builtin_amdgcn_s_setprio(1);
#pragma unroll
      for (int ks = 0; ks < 4; ++ks) s = MFMA32(kf[ks], qf[ks], s);
      __builtin_amdgcn_s_setprio(0);

      float p[16];
      if (um) {
        const size_t mrow = (size_t)(q0 + lq) * 2048 + kv0 + s32 * 32;
#pragma unroll
        for (int i = 0; i < 16; ++i)
          p[i] = s[i] + mask[mrow + (i & 3) + 8 * (i >> 2) + 4 * hi] * LOG2E;
      } else {
#pragma unroll
        for (int i = 0; i < 16; ++i) p[i] = s[i];
      }

      float t = fmaxf(fmaxf(p[0], p[1]), p[2]);
      t = fmaxf(fmaxf(t, p[3]), p[4]);
      t = fmaxf(fmaxf(t, p[5]), p[6]);
      t = fmaxf(fmaxf(t, p[7]), p[8]);
      t = fmaxf(fmaxf(t, p[9]), p[10]);
      t = fmaxf(fmaxf(t, p[11]), p[12]);
      t = fmaxf(fmaxf(t, p[13]), p[14]);
      t = fmaxf(t, p[15]);
      t = fmaxf(t, __shfl_xor(t, 32));

      if (t > mrun + 8.f) {
        const float al = exp2_fast(mrun - t);
        mrun = t;
        lrun *= al;
#pragma unroll
        for (int i = 0; i < 16; ++i) { o0[i] *= al; o1[i] *= al; }
      }

      float ps = 0.f;
#pragma unroll
      for (int i = 0; i < 16; ++i) { p[i] = exp2_fast(p[i] - mrun); ps += p[i]; }
      lrun += ps;

      bf16x8 pa[2];
#pragma unroll
      for (int ks = 0; ks < 2; ++ks) {
        unsigned int c0 = cvtpk_bf16(p[8 * ks + 0], p[8 * ks + 1]);
        unsigned int c1 = cvtpk_bf16(p[8 * ks + 2], p[8 * ks + 3]);
        unsigned int c2 = cvtpk_bf16(p[8 * ks + 4], p[8 * ks + 5]);
        unsigned int c3 = cvtpk_bf16(p[8 * ks + 6], p[8 * ks + 7]);
        permswap(c0, c2);
        permswap(c1, c3);
        u32x4 wv; wv.x = c0; wv.y = c1; wv.z = c2; wv.w = c3;
        pa[ks] = __builtin_bit_cast(bf16x8, wv);
      }

      __builtin_amdgcn_s_setprio(1);
#pragma unroll
      for (int ks = 0; ks < 2; ++ks) {
        const int kvb = s32 * 64 + ks * 32 + hi * 16;
        bf16x8 v0 = *(const bf16x8*)(Vc + krow + ((0 + kvb) ^ swz));
        bf16x8 v1 = *(const bf16x8*)(Vc + krow + ((128 + kvb) ^ swz));
        o0 = MFMA32(v0, pa[ks], o0);
        o1 = MFMA32(v1, pa[ks], o1);
      }
      __builtin_amdgcn_s_setprio(0);
    }
    __syncthreads();
    char* tk = Kc; Kc = Kn; Kn = tk;
    char* tv = Vc; Vc = Vn; Vn = tv;
  }

  lrun += __shfl_xor(lrun, 32);
  const float inv = 1.f / lrun;
  const size_t base = ((size_t)(b * 2048 + q0 + lq)) * 1024 + h * 64;
#pragma unroll
  for (int half = 0; half < 2; ++half) {
#pragma unroll
    for (int g = 0; g < 4; ++g) {
      const int d0 = half * 32 + g * 8 + hi * 4;
      bf16x4 g4 = *(const bf16x4*)(G + base + d0);
      bf16x4 r4;
#pragma unroll
      for (int j = 0; j < 4; ++j) {
        const float ov = half ? o1[g * 4 + j] : o0[g * 4 + j];
        r4[j] = (__bf16)(ov * inv * (float)g4[j]);
      }
      *(bf16x4*)(attn + base + d0) = r4;
    }
  }
}

// ---------------- O projection (bf16 in, fp32 out), 2-phase dbuf ----------------
__global__ __launch_bounds__(256) void oproj_kernel(
    const __bf16* __restrict__ A, const __bf16* __restrict__ ow,
    const float* __restrict__ ob, float* __restrict__ C)
{
  __shared__ __bf16 As[2][128][64];
  __shared__ __bf16 Bs[2][128][64];
  const int bid = blockIdx.x;
  const int ntile = bid & 7;
  const int mtile = bid >> 3;
  const int m0 = mtile * 128, n0 = ntile * 128;

  const int tid = threadIdx.x;
  const int wv = tid >> 6, ln = tid & 63;
  const int wr = wv >> 1, wc = wv & 1;
  const int qr = ln & 15, qg = ln >> 4;
  const int lrow = ln >> 3, lcol = (ln & 7) * 8;

  f32x4 acc[4][4];
#pragma unroll
  for (int m = 0; m < 4; ++m)
#pragma unroll
    for (int n = 0; n < 4; ++n) acc[m][n] = 0.f;

  __bf16 (*Asc)[64] = As[0], (*Asn)[64] = As[1];
  __bf16 (*Bsc)[64] = Bs[0], (*Bsn)[64] = Bs[1];

#pragma unroll
  for (int i = 0; i < 4; ++i) {
    const int rb = i * 32 + wv * 8;
    gload16(A  + (size_t)(m0 + rb + lrow) * 1024 + lcol, &Asc[rb][0]);
    gload16(ow + (size_t)(n0 + rb + lrow) * 1024 + lcol, &Bsc[rb][0]);
  }
  __syncthreads();

  for (int t = 0; t < 16; ++t) {
    if (t < 15) {
      const int k0 = (t + 1) * 64;
#pragma unroll
      for (int i = 0; i < 4; ++i) {
        const int rb = i * 32 + wv * 8;
        gload16(A  + (size_t)(m0 + rb + lrow) * 1024 + k0 + lcol, &Asn[rb][0]);
        gload16(ow + (size_t)(n0 + rb + lrow) * 1024 + k0 + lcol, &Bsn[rb][0]);
      }
    }
#pragma unroll
    for (int kk = 0; kk < 2; ++kk) {
      bf16x8 af[4], bfv[4];
#pragma unroll
      for (int m = 0; m < 4; ++m) af[m] = *(const bf16x8*)&Asc[wr * 64 + m * 16 + qr][kk * 32 + qg * 8];
#pragma unroll
      for (int n = 0; n < 4; ++n) bfv[n] = *(const bf16x8*)&Bsc[wc * 64 + n * 16 + qr][kk * 32 + qg * 8];
#pragma unroll
      for (int m = 0; m < 4; ++m)
#pragma unroll
        for (int n = 0; n < 4; ++n) acc[m][n] = MFMA_BF16(af[m], bfv[n], acc[m][n]);
    }
    __syncthreads();
    __bf16 (*ta)[64] = Asc; Asc = Asn; Asn = ta;
    __bf16 (*tb)[64] = Bsc; Bsc = Bsn; Bsn = tb;
  }

#pragma unroll
  for (int m = 0; m < 4; ++m) {
    const int gm0 = m0 + wr * 64 + m * 16 + qg * 4;
#pragma unroll
    for (int n = 0; n < 4; ++n) {
      const int gn = n0 + wc * 64 + n * 16 + qr;
      const float bb = ob[gn];
      float* dst = C + (size_t)gm0 * 1024 + gn;
#pragma unroll
      for (int rr = 0; rr < 4; ++rr) dst[(size_t)rr * 1024] = acc[m][n][rr] + bb;
    }
  }
}

extern "C" void kernel_launch(void* const* d_in, const int* in_sizes, int n_in,
                              void* d_out, int out_size, void* d_ws, size_t ws_size,
                              hipStream_t stream)
{
  const float* hs   = (const float*)d_in[0];
  const float* mask = (const float*)d_in[1];
  const float* qw   = (const float*)d_in[2];
  const float* qb   = (const float*)d_in[3];
  const float* kw   = (const float*)d_in[4];
  const float* kb   = (const float*)d_in[5];
  const float* vw   = (const float*)d_in[6];
  const float* vb   = (const float*)d_in[7];
  const float* ow   = (const float*)d_in[8];
  const float* ob   = (const float*)d_in[9];
  float* out = (float*)d_out;

  char* w = (char*)d_ws;
  int*    flag = (int*)w;
  __bf16* Xb  = (__bf16*)(w + 256);
  __bf16* qwb = Xb  + 4194304;
  __bf16* kwb = qwb + 2097152;
  __bf16* vwb = kwb + 1048576;
  __bf16* owb = vwb + 1048576;
  __bf16* Qo  = owb + 1048576;
  __bf16* Ko  = Qo  + 4194304;
  __bf16* VTo = Ko  + 4194304;
  __bf16* Go  = VTo + 4194304;
  __bf16* At  = Go  + 4194304;

  hipFuncSetAttribute((const void*)proj_kernel, hipFuncAttributeMaxDynamicSharedMemorySize, 131072);

  hipMemsetAsync(flag, 0, sizeof(int), stream);
  cvt_all_kernel<<<2048, 256, 0, stream>>>(hs, qw, kw, vw, ow, Xb, qwb, kwb, vwb, owb,
                                           (const unsigned long long*)mask, flag);
  proj_kernel<<<256, 512, 131072, stream>>>(Xb, qwb, qb, kwb, kb, vwb, vb, Qo, Ko, VTo, Go);
  attn_kernel<<<512, 256, 0, stream>>>(Qo, Ko, VTo, Go, mask, flag, At);
  oproj_kernel<<<256, 256, 0, stream>>>(At, owb, ob, out);
}